// Round 13
// baseline (442.243 us; speedup 1.0000x reference)
//
#include <hip/hip_runtime.h>
#include <hip/hip_bf16.h>
#include <math.h>

#define DEV __device__ __forceinline__

DEV float frn_mul(float a, float b) { return __fmul_rn(a, b); }
DEV float frn_add(float a, float b) { return __fadd_rn(a, b); }

union BFU { __hip_bfloat16 h; unsigned short u; };

typedef __attribute__((ext_vector_type(8))) short short8v;  // 8 bf16 (4 VGPRs)
typedef __attribute__((ext_vector_type(4))) float f32x4;

// ---------------------------------------------------------------------------
// pack verts [n][3] -> float4 (x,y,z,|p|^2) with pn in exact frn order.
// ---------------------------------------------------------------------------
__global__ void pack4_kernel(const float* __restrict__ v, float4* __restrict__ out,
                             int n)
{
    int t = blockIdx.x * blockDim.x + threadIdx.x;
    if (t >= n) return;
    float x = v[(size_t)t * 3 + 0], y = v[(size_t)t * 3 + 1], z = v[(size_t)t * 3 + 2];
    float pn = frn_add(frn_add(frn_mul(x, x), frn_mul(y, y)), frn_mul(z, z));
    out[t] = make_float4(x, y, z, pn);
}

// ---------------------------------------------------------------------------
// qb scan body, 2-deep pipelined (128-pt granularity). V % 128 == 0.
// pts buffer must allow reads up to V+255 within allocation (padded).
// ---------------------------------------------------------------------------
DEV void qb_scan2(const float4* __restrict__ pts, int V, float4 q4, float r2,
                  int lane, int* __restrict__ row)
{
    float qx = q4.x, qy = q4.y, qz = q4.z, qn = q4.w;
    int count = 0;
    int first = -1;
    float4 pbuf[2];
#pragma unroll
    for (int u = 0; u < 2; ++u) pbuf[u] = pts[u * 64 + lane];
    for (int base = 0; base < V && count < 32; base += 128) {
#pragma unroll
        for (int u = 0; u < 2; ++u) {
            float4 p = pbuf[u];
            pbuf[u] = pts[base + 128 + u * 64 + lane];
            float dt = frn_add(frn_add(frn_mul(qx, p.x), frn_mul(qy, p.y)), frn_mul(qz, p.z));
            float d = __fsub_rn(frn_add(qn, p.w), frn_mul(2.0f, dt));
            bool in = !(d > r2);
            unsigned long long mask = __ballot(in);
            if (first < 0 && mask != 0ull)
                first = base + u * 64 + (int)__ffsll((long long)mask) - 1;
            int pos = count + (int)__popcll(mask & ((1ull << lane) - 1ull));
            if (in && pos < 32) row[pos] = base + u * 64 + lane;
            count += (int)__popcll(mask);
        }
    }
    int cnt = count < 32 ? count : 32;
    for (int t = cnt + lane; t < 32; t += 64) row[t] = first;
}

// ---------------------------------------------------------------------------
// MEGA start kernel: block ranges
//  [0,16384)        : L1 qb cooperative (1 block = 1 query, 4 waves scan
//                     256 pts/iter, ballot-merge via LDS) + conv_surface
//  [16384,18432)    : qb L2 (V=2048, r2=0.16) -> idx2
//  [18432,19456)    : qb L3 (V=1024, r2=0.36) -> idx3
//  [19456,19968)    : qb L4 (V=512,  r2=0.64) -> idx4
//  [19968,20224)    : qb L5 (V=256,  r2=1.0)  -> idx5
//  [20224,20944)    : castT w11 [288][5120] f32 -> WTbf [5120][288] bf16
// All qb phases read only vp1 (batch stride 4096, padded).
// ---------------------------------------------------------------------------
__global__ __launch_bounds__(256)
void mega_start_kernel(const float4* __restrict__ vp1,
                       const float* __restrict__ dirs, // (3,128) surf
                       float* __restrict__ outF, int Cw,
                       int* __restrict__ idx1, int* __restrict__ idx2,
                       int* __restrict__ idx3, int* __restrict__ idx4,
                       int* __restrict__ idx5,
                       const float* __restrict__ w11, unsigned short* __restrict__ wt)
{
    __shared__ unsigned long long maskL[2][4];
    __shared__ int rowS[32];
    __shared__ float MS[128];
    int bid = blockIdx.x;
    int tid = threadIdx.x;
    int lane = tid & 63;

    if (bid < 16384) {
        // ---- L1 cooperative qb + surface (V=4096) ----
        int wid = bid;
        int b = wid >> 12;
        int wave = tid >> 6;
        float4 q4 = vp1[(size_t)wid];
        float qx = q4.x, qy = q4.y, qz = q4.z, qn = q4.w;
        const float4* pts = vp1 + (size_t)b * 4096;
        int* row = idx1 + (size_t)wid * 32;
        unsigned long long lmask = (1ull << lane) - 1ull;

        int count = 0;
        int first = -1;
        int ib = 0;
        float4 p = pts[wave * 64 + lane];
        for (int base = 0; base < 4096 && count < 32; base += 256, ib ^= 1) {
            float4 pnx = pts[base + 256 + wave * 64 + lane];   // prefetch (padded)
            float dt = frn_add(frn_add(frn_mul(qx, p.x), frn_mul(qy, p.y)), frn_mul(qz, p.z));
            float d = __fsub_rn(frn_add(qn, p.w), frn_mul(2.0f, dt));
            bool in = !(d > 0.04f);
            unsigned long long mask = __ballot(in);
            if (lane == 0) maskL[ib][wave] = mask;
            __syncthreads();
            unsigned long long m0 = maskL[ib][0], m1 = maskL[ib][1];
            unsigned long long m2 = maskL[ib][2], m3 = maskL[ib][3];
            int c0 = (int)__popcll(m0), c1 = (int)__popcll(m1);
            int c2 = (int)__popcll(m2), c3 = (int)__popcll(m3);
            if (first < 0) {
                if (m0) first = base + (int)__ffsll((long long)m0) - 1;
                else if (m1) first = base + 64 + (int)__ffsll((long long)m1) - 1;
                else if (m2) first = base + 128 + (int)__ffsll((long long)m2) - 1;
                else if (m3) first = base + 192 + (int)__ffsll((long long)m3) - 1;
            }
            int off = count;
            if (wave > 0) off += c0;
            if (wave > 1) off += c1;
            if (wave > 2) off += c2;
            int pos = off + (int)__popcll(mask & lmask);
            if (in && pos < 32) {
                int vv = base + wave * 64 + lane;
                row[pos] = vv; rowS[pos] = vv;
            }
            count += c0 + c1 + c2 + c3;
            p = pnx;
        }
        int cnt = count < 32 ? count : 32;
        for (int t = cnt + tid; t < 32; t += 256) { row[t] = first; rowS[t] = first; }
        __syncthreads();

        if (wave < 2) {
            int k = lane & 31;
            float4 nb4 = pts[rowS[k]];
            float dx = nb4.x - qx;
            float dy = nb4.y - qy;
            float dz = nb4.z - qz;
            float nrm = sqrtf(dx * dx + dy * dy + dz * dz) + 1e-12f;
            float inv = 1.0f / nrm;
            float dnx = dx * inv, dny = dy * inv, dnz = dz * inv;
            int m = wave * 64 + lane;
            float ax = dirs[m], ay = dirs[128 + m], az = dirs[256 + m];
            float i1 = 1.0f / (sqrtf(ax * ax + ay * ay + az * az) + 1e-12f);
            ax *= i1; ay *= i1; az *= i1;
            float mx = -INFINITY;
            for (int k2 = 0; k2 < 32; ++k2) {
                float ex = __shfl(dnx, k2, 64);
                float ey = __shfl(dny, k2, 64);
                float ez = __shfl(dnz, k2, 64);
                float t1 = fmaxf(ex * ax + ey * ay + ez * az, 0.0f);
                mx = fmaxf(mx, t1);
            }
            MS[m] = mx;
        }
        __syncthreads();
        if (tid < 32) {
            float s0 = MS[tid] + MS[tid + 64];
            float s1 = MS[tid + 32] + MS[tid + 96];
            outF[(size_t)wid * Cw + tid] = fmaxf(s0 + s1, 0.0f);
        }
    } else if (bid < 20224) {
        int V, r_bid; float r2; int* idxp;
        if (bid < 18432)      { V = 2048; r2 = 0.16f; idxp = idx2; r_bid = bid - 16384; }
        else if (bid < 19456) { V = 1024; r2 = 0.36f; idxp = idx3; r_bid = bid - 18432; }
        else if (bid < 19968) { V = 512;  r2 = 0.64f; idxp = idx4; r_bid = bid - 19456; }
        else                  { V = 256;  r2 = 1.0f;  idxp = idx5; r_bid = bid - 19968; }
        int widl = (r_bid * 256 + tid) >> 6;      // 0 .. 4*V-1
        int b = widl / V;
        int v = widl - b * V;
        float4 q4 = vp1[(size_t)b * 4096 + v];
        const float4* pts = vp1 + (size_t)b * 4096;
        qb_scan2(pts, V, q4, r2, lane, idxp + (size_t)widl * 32);
    } else {
        // ---- castT: w11 -> WTbf ----
        int t = (bid - 20224) * 256 + tid;
        if (t < 5120 * 36) {
            int kc = t / 5120;
            int n = t - kc * 5120;
            BFU a;
            ushort4 o0, o1;
            a.h = __float2bfloat16(w11[(size_t)(kc * 8 + 0) * 5120 + n]); o0.x = a.u;
            a.h = __float2bfloat16(w11[(size_t)(kc * 8 + 1) * 5120 + n]); o0.y = a.u;
            a.h = __float2bfloat16(w11[(size_t)(kc * 8 + 2) * 5120 + n]); o0.z = a.u;
            a.h = __float2bfloat16(w11[(size_t)(kc * 8 + 3) * 5120 + n]); o0.w = a.u;
            a.h = __float2bfloat16(w11[(size_t)(kc * 8 + 4) * 5120 + n]); o1.x = a.u;
            a.h = __float2bfloat16(w11[(size_t)(kc * 8 + 5) * 5120 + n]); o1.y = a.u;
            a.h = __float2bfloat16(w11[(size_t)(kc * 8 + 6) * 5120 + n]); o1.z = a.u;
            a.h = __float2bfloat16(w11[(size_t)(kc * 8 + 7) * 5120 + n]); o1.w = a.u;
            *(ushort4*)&wt[(size_t)n * 288 + kc * 8] = o0;
            *(ushort4*)&wt[(size_t)n * 288 + kc * 8 + 4] = o1;
        }
    }
}

// ---------------------------------------------------------------------------
// Tiled GEMM (64x64, 4x4 micro): small-N layer GEMMs (fp32, proven).
// ---------------------------------------------------------------------------
__global__ __launch_bounds__(256)
void gemm_tiled_kernel(const float* __restrict__ feat, int Cw, int cin,
                       const float* __restrict__ w, const float* __restrict__ bias,
                       int N, float* __restrict__ fout)
{
    __shared__ float As[64][36];
    __shared__ float Bs[32][68];

    int m0 = blockIdx.x * 64;
    int n0 = blockIdx.y * 64;
    int tid = threadIdx.x;
    int tx = tid & 15, ty = tid >> 4;

    float acc[4][4];
#pragma unroll
    for (int i = 0; i < 4; ++i)
#pragma unroll
        for (int j = 0; j < 4; ++j) acc[i][j] = 0.0f;

    for (int k0 = 0; k0 < cin; k0 += 32) {
#pragma unroll
        for (int i = 0; i < 2; ++i) {
            int qq = tid + i * 256;
            int row = qq >> 3, c = qq & 7;
            float4 v = *(const float4*)&feat[(size_t)(m0 + row) * Cw + k0 + 4 * c];
            *(float4*)&As[row][4 * c] = v;
        }
#pragma unroll
        for (int i = 0; i < 2; ++i) {
            int qq = tid + i * 256;
            int kr = qq >> 4, c = qq & 15;
            int n = n0 + 4 * c;
            float4 v = make_float4(0.0f, 0.0f, 0.0f, 0.0f);
            if (n < N) v = *(const float4*)&w[(size_t)(k0 + kr) * N + n];
            *(float4*)&Bs[kr][4 * c] = v;
        }
        __syncthreads();

#pragma unroll
        for (int kt = 0; kt < 32; kt += 4) {
            float4 av4[4], bv4[4];
#pragma unroll
            for (int i = 0; i < 4; ++i) av4[i] = *(const float4*)&As[ty * 4 + i][kt];
#pragma unroll
            for (int r = 0; r < 4; ++r) bv4[r] = *(const float4*)&Bs[kt + r][tx * 4];
            const float* a = (const float*)av4;
            const float* bb = (const float*)bv4;
#pragma unroll
            for (int i = 0; i < 4; ++i)
#pragma unroll
                for (int r = 0; r < 4; ++r)
#pragma unroll
                    for (int j = 0; j < 4; ++j)
                        acc[i][j] = fmaf(a[i * 4 + r], bb[r * 4 + j], acc[i][j]);
        }
        __syncthreads();
    }

    int n = n0 + tx * 4;
    if (n < N) {
        float b0 = bias[n + 0], b1 = bias[n + 1], b2 = bias[n + 2], b3 = bias[n + 3];
#pragma unroll
        for (int i = 0; i < 4; ++i) {
            int m = m0 + ty * 4 + i;
            float4 o;
            o.x = acc[i][0] + b0;
            o.y = acc[i][1] + b1;
            o.z = acc[i][2] + b2;
            o.w = acc[i][3] + b3;
            *(float4*)&fout[(size_t)m * N + n] = o;
        }
    }
}

// ---------------------------------------------------------------------------
// conv11 GEMM via bf16 MFMA (M=1024, K=288, N=5120). 128x128 tile, 4 waves.
// ---------------------------------------------------------------------------
__global__ __launch_bounds__(256)
void gemm_mfma_conv11(const unsigned short* __restrict__ Abf,
                      const unsigned short* __restrict__ WTbf,
                      const float* __restrict__ bias,
                      __hip_bfloat16* __restrict__ fout)
{
    __shared__ unsigned short As[128][40];
    __shared__ unsigned short Bs[128][40];
    const int K = 288, N = 5120;
    int m0 = blockIdx.x * 128;
    int n0 = blockIdx.y * 128;
    int tid = threadIdx.x;
    int lane = tid & 63;
    int wave = tid >> 6;
    int wm = wave & 1, wn = wave >> 1;
    int l15 = lane & 15, l4 = lane >> 4;

    f32x4 acc[4][4];
#pragma unroll
    for (int mi = 0; mi < 4; ++mi)
#pragma unroll
        for (int ni = 0; ni < 4; ++ni) acc[mi][ni] = (f32x4){0.f, 0.f, 0.f, 0.f};

    for (int k0 = 0; k0 < K; k0 += 32) {
#pragma unroll
        for (int i = 0; i < 2; ++i) {
            int c = tid + i * 256;
            int row = c >> 2, qq = c & 3;
            *(uint4*)&As[row][qq * 8] = *(const uint4*)&Abf[(size_t)(m0 + row) * K + k0 + qq * 8];
            *(uint4*)&Bs[row][qq * 8] = *(const uint4*)&WTbf[(size_t)(n0 + row) * K + k0 + qq * 8];
        }
        __syncthreads();

        short8v af[4], bfv[4];
#pragma unroll
        for (int mi = 0; mi < 4; ++mi)
            af[mi] = *(const short8v*)&As[wm * 64 + mi * 16 + l15][l4 * 8];
#pragma unroll
        for (int ni = 0; ni < 4; ++ni)
            bfv[ni] = *(const short8v*)&Bs[wn * 64 + ni * 16 + l15][l4 * 8];
#pragma unroll
        for (int mi = 0; mi < 4; ++mi)
#pragma unroll
            for (int ni = 0; ni < 4; ++ni)
                acc[mi][ni] = __builtin_amdgcn_mfma_f32_16x16x32_bf16(af[mi], bfv[ni], acc[mi][ni], 0, 0, 0);
        __syncthreads();
    }

#pragma unroll
    for (int ni = 0; ni < 4; ++ni) {
        int col = n0 + wn * 64 + ni * 16 + l15;
        float bv = bias[col];
#pragma unroll
        for (int mi = 0; mi < 4; ++mi) {
            int rbase = m0 + wm * 64 + mi * 16 + l4 * 4;
#pragma unroll
            for (int j = 0; j < 4; ++j) {
                BFU u;
                u.h = __float2bfloat16(acc[mi][ni][j] + bv);
                *(unsigned short*)&fout[(size_t)(rbase + j) * N + col] = u.u;
            }
        }
    }
}

// ---------------------------------------------------------------------------
// conv_layer aggregation, cout=32. One wave per (b,v), XCD-swizzled.
// Verts in vp1 (batch stride 4096). Optional bf16 mirror (L5 -> Abf col 256+).
// ---------------------------------------------------------------------------
__global__ void conv_agg32_kernel(const int* __restrict__ idx,
                                  const float4* __restrict__ vp1,
                                  const float* __restrict__ fout,
                                  const float* __restrict__ dirs, // (3,128)
                                  float* __restrict__ outF, int Cw, int coff,
                                  int V, int do_relu,
                                  unsigned short* __restrict__ abf)
{
    int blk = blockIdx.x;
    int b = (blk & 7) >> 1;
    int j = ((blk >> 3) << 1) | (blk & 1);
    int vloc = j * 4 + (int)(threadIdx.x >> 6);
    int wid = b * V + vloc;
    int lane = threadIdx.x & 63;

    float dnx, dny, dnz;
    int nbrow;
    {
        int k = lane & 31;
        int nb = idx[(size_t)wid * 32 + k];
        nbrow = b * V + nb;
        float4 c4 = vp1[(size_t)b * 4096 + vloc];
        float4 n4 = vp1[(size_t)b * 4096 + nb];
        float dx = n4.x - c4.x;
        float dy = n4.y - c4.y;
        float dz = n4.z - c4.z;
        float nrm = sqrtf(dx * dx + dy * dy + dz * dz) + 1e-12f;
        float inv = 1.0f / nrm;
        dnx = dx * inv; dny = dy * inv; dnz = dz * inv;
    }
    int m1 = lane, m2 = lane + 64;
    float ax = dirs[m1], ay = dirs[128 + m1], az = dirs[256 + m1];
    float i1 = 1.0f / (sqrtf(ax * ax + ay * ay + az * az) + 1e-12f);
    ax *= i1; ay *= i1; az *= i1;
    float bx = dirs[m2], by = dirs[128 + m2], bz = dirs[256 + m2];
    float i2 = 1.0f / (sqrtf(bx * bx + by * by + bz * bz) + 1e-12f);
    bx *= i2; by *= i2; bz *= i2;

    float a1[4] = {-INFINITY, -INFINITY, -INFINITY, -INFINITY};
    float a2[4] = {-INFINITY, -INFINITY, -INFINITY, -INFINITY};
#pragma unroll
    for (int kk = 0; kk < 32; kk += 4) {
#pragma unroll
        for (int u = 0; u < 4; ++u) {
            int k = kk + u;
            float ex = __shfl(dnx, k, 64);
            float ey = __shfl(dny, k, 64);
            float ez = __shfl(dnz, k, 64);
            int nr = __shfl(nbrow, k, 64);
            const float* fr = fout + (size_t)nr * 160 + 32;
            float t1 = fmaxf(ex * ax + ey * ay + ez * az, 0.0f);
            float t2 = fmaxf(ex * bx + ey * by + ez * bz, 0.0f);
            a1[u] = fmaxf(a1[u], t1 * fr[m1]);
            a2[u] = fmaxf(a2[u], t2 * fr[m2]);
        }
    }
    float mx1 = fmaxf(fmaxf(a1[0], a1[1]), fmaxf(a1[2], a1[3]));
    float mx2 = fmaxf(fmaxf(a2[0], a2[1]), fmaxf(a2[2], a2[3]));
    float part = mx1 + mx2;
    float tot = part + __shfl_xor(part, 32, 64);
    if (lane < 32) {
        float c = fout[(size_t)wid * 160 + lane];
        float val = c + tot;
        if (do_relu) val = fmaxf(val, 0.0f);
        outF[(size_t)wid * Cw + coff + lane] = val;
        if (abf) {
            BFU u; u.h = __float2bfloat16(val);
            abf[(size_t)wid * 288 + coff + lane] = u.u;
        }
    }
}

// ---------------------------------------------------------------------------
// conv11 aggregation: cout=1024. One 512-thread block per (b,v). Thread t
// owns 8 pairs [8t,8t+8). Row offsets hoisted to LDS; k-loop unrolled x2.
// Padded-LDS regroup (pad 9), exact original ((s0+s1)+s2)+s3 order.
// ---------------------------------------------------------------------------
__global__ __launch_bounds__(512)
void conv_agg_big_kernel(const int* __restrict__ idx,
                         const float4* __restrict__ vp1,
                         const __hip_bfloat16* __restrict__ fout,
                         const float* __restrict__ dirs,
                         float* __restrict__ G,
                         int V, int B)
{
    __shared__ float dnS[32][3];
    __shared__ long long offS[32];
    __shared__ float sm[512 * 9];
    int blk = blockIdx.x;
    int b = (blk & 7) >> 1;
    int v = ((blk >> 3) << 1) | (blk & 1);
    int row = b * V + v;
    int tid = threadIdx.x;

    if (tid < 32) {
        int nb = idx[(size_t)row * 32 + tid];
        float4 c4 = vp1[(size_t)b * 4096 + v];
        float4 n4 = vp1[(size_t)b * 4096 + nb];
        float dx = n4.x - c4.x;
        float dy = n4.y - c4.y;
        float dz = n4.z - c4.z;
        float nrm = sqrtf(dx * dx + dy * dy + dz * dz) + 1e-12f;
        float inv = 1.0f / nrm;
        dnS[tid][0] = dx * inv; dnS[tid][1] = dy * inv; dnS[tid][2] = dz * inv;
        offS[tid] = (long long)(b * V + nb) * 5120 + 1024;
    }
    __syncthreads();

    int p0 = tid * 8;
    float4 X[2], Y[2], Z[2];
#pragma unroll
    for (int c = 0; c < 2; ++c) {
        X[c] = *(const float4*)&dirs[p0 + 4 * c];
        Y[c] = *(const float4*)&dirs[4096 + p0 + 4 * c];
        Z[c] = *(const float4*)&dirs[8192 + p0 + 4 * c];
    }
    const float* xf = (const float*)X;
    const float* yf = (const float*)Y;
    const float* zf = (const float*)Z;
    float sdx[8], sdy[8], sdz[8], mx[8];
#pragma unroll
    for (int p = 0; p < 8; ++p) {
        float ax = xf[p], ay = yf[p], az = zf[p];
        float inv = 1.0f / (sqrtf(ax * ax + ay * ay + az * az) + 1e-12f);
        sdx[p] = ax * inv; sdy[p] = ay * inv; sdz[p] = az * inv;
        mx[p] = -INFINITY;
    }

#pragma unroll 2
    for (int k = 0; k < 32; ++k) {
        float ex = dnS[k][0], ey = dnS[k][1], ez = dnS[k][2];
        const __hip_bfloat16* fr = fout + offS[k];
        uint4 u0 = *(const uint4*)&fr[p0];
        unsigned int uu[4] = {u0.x, u0.y, u0.z, u0.w};
#pragma unroll
        for (int h = 0; h < 4; ++h) {
            float slo = __uint_as_float(uu[h] << 16);
            float shi = __uint_as_float(uu[h] & 0xFFFF0000u);
            int p = 2 * h;
            float th0 = fmaxf(ex * sdx[p] + ey * sdy[p] + ez * sdz[p], 0.0f);
            float th1 = fmaxf(ex * sdx[p + 1] + ey * sdy[p + 1] + ez * sdz[p + 1], 0.0f);
            mx[p] = fmaxf(mx[p], th0 * slo);
            mx[p + 1] = fmaxf(mx[p + 1], th1 * shi);
        }
    }

#pragma unroll
    for (int p = 0; p < 8; ++p) sm[tid * 9 + p] = mx[p];
    __syncthreads();

#pragma unroll
    for (int q = 0; q < 2; ++q) {
        int oo = q * 512 + tid;
        int t0 = oo >> 3, pp = oo & 7;
        float s0 = sm[t0 * 9 + pp];
        float s1 = sm[(128 + t0) * 9 + pp];
        float s2 = sm[(256 + t0) * 9 + pp];
        float s3 = sm[(384 + t0) * 9 + pp];
        float val = ((s0 + s1) + s2) + s3;
        float c = __bfloat162float(fout[(size_t)row * 5120 + oo]);
        G[(size_t)row * 1024 + oo] = c + val;
    }
}

// ---------------------------------------------------------------------------
// Pool: reuses conv idx (first 4). Pure feature gather (+ optional bf16
// mirror for the conv11 A-matrix at L4->L5).
// ---------------------------------------------------------------------------
__global__ void pool_fused_kernel(const int* __restrict__ idx_conv,
                                  int Vp, int Vh, int B,
                                  const float* __restrict__ Fin, int CwIn,
                                  float* __restrict__ Fout, int CwOut, int C,
                                  unsigned short* __restrict__ abf)
{
    int wid = (blockIdx.x * blockDim.x + threadIdx.x) >> 6;
    int lane = threadIdx.x & 63;
    int nq = B * Vh;
    if (wid >= nq) return;
    int b = wid / Vh;
    int v = wid - b * Vh;
    int rowc = b * Vp + v;

    int idv = 0;
    if (lane < 4) idv = idx_conv[(size_t)rowc * 32 + lane];
    int i0 = __shfl(idv, 0, 64);
    int i1 = __shfl(idv, 1, 64);
    int i2 = __shfl(idv, 2, 64);
    int i3 = __shfl(idv, 3, 64);

    const float* r0 = Fin + (size_t)(b * Vp + i0) * CwIn;
    const float* r1 = Fin + (size_t)(b * Vp + i1) * CwIn;
    const float* r2p = Fin + (size_t)(b * Vp + i2) * CwIn;
    const float* r3 = Fin + (size_t)(b * Vp + i3) * CwIn;
    for (int c = lane; c < C; c += 64) {
        float m = fmaxf(fmaxf(r0[c], r1[c]), fmaxf(r2p[c], r3[c]));
        Fout[(size_t)wid * CwOut + c] = m;
        if (abf) {
            BFU u; u.h = __float2bfloat16(m);
            abf[(size_t)wid * 288 + c] = u.u;
        }
    }
}

// ---------------------------------------------------------------------------
// Head
// ---------------------------------------------------------------------------
__global__ void gmax_kernel(const float* __restrict__ G, float* __restrict__ gm,
                            int V)
{
    __shared__ float red[4][64];
    int b = blockIdx.x >> 4;
    int c0 = (blockIdx.x & 15) * 64;
    int t = threadIdx.x;
    int c = c0 + (t & 63);
    int vg = t >> 6;
    float m = -INFINITY;
    for (int v = vg * 64; v < (vg + 1) * 64; ++v)
        m = fmaxf(m, G[((size_t)b * V + v) * 1024 + c]);
    red[vg][t & 63] = m;
    __syncthreads();
    if (t < 64) {
        float r = fmaxf(fmaxf(red[0][t], red[1][t]), fmaxf(red[2][t], red[3][t]));
        gm[b * 1024 + c0 + t] = r;
    }
}

__global__ __launch_bounds__(256)
void fc1_kernel(const float* __restrict__ gm, const float* __restrict__ w1,
                const float* __restrict__ b1_,
                const float* __restrict__ bn_g, const float* __restrict__ bn_b,
                const float* __restrict__ bn_m, const float* __restrict__ bn_v,
                float* __restrict__ h)
{
    __shared__ float gs[1024];
    __shared__ float red[8][32];
    int b = blockIdx.y;
    int j0 = blockIdx.x * 32;
    int t = threadIdx.x;
    for (int i = t; i < 1024; i += 256) gs[i] = gm[b * 1024 + i];
    __syncthreads();
    int jj = t & 31, kk = t >> 5;
    int j = j0 + jj;
    const float* wp = w1 + (size_t)(kk * 128) * 256 + j;
    float acc = 0.0f;
#pragma unroll 8
    for (int k = 0; k < 128; ++k)
        acc = fmaf(gs[kk * 128 + k], wp[(size_t)k * 256], acc);
    red[kk][jj] = acc;
    __syncthreads();
    if (t < 32) {
        float s = 0.0f;
#pragma unroll
        for (int q = 0; q < 8; ++q) s += red[q][t];
        int jw = j0 + t;
        s += b1_[jw];
        s = (s - bn_m[jw]) / sqrtf(bn_v[jw] + 1e-5f) * bn_g[jw] + bn_b[jw];
        h[b * 256 + jw] = fmaxf(s, 0.0f);
    }
}

__global__ void fc2_kernel(const float* __restrict__ h, const float* __restrict__ w2,
                           const float* __restrict__ b2_, float* __restrict__ out)
{
    __shared__ float hs[256];
    int b = blockIdx.x;
    int t = threadIdx.x;
    hs[t] = h[b * 256 + t];
    __syncthreads();
    if (t < 40) {
        float acc = 0.0f;
#pragma unroll 8
        for (int k = 0; k < 256; ++k) acc = fmaf(hs[k], w2[(size_t)k * 40 + t], acc);
        out[b * 40 + t] = acc + b2_[t];
    }
}

// ---------------------------------------------------------------------------
static inline int wblocks(int waves) { return (waves + 3) / 4; }
static inline int tblocks(int threads) { return (threads + 255) / 256; }
static inline dim3 ggrid(int M, int N) { return dim3(M / 64, (N + 63) / 64); }

extern "C" void kernel_launch(void* const* d_in, const int* in_sizes, int n_in,
                              void* d_out, int out_size, void* d_ws, size_t ws_size,
                              hipStream_t stream)
{
    const int B = 4;
    const float* verts1 = (const float*)d_in[0];
    const float* surf_dirs = (const float*)d_in[1];
    const float* w1 = (const float*)d_in[2];
    const float* b1 = (const float*)d_in[3];
    const float* d1 = (const float*)d_in[4];
    const float* w3 = (const float*)d_in[5];
    const float* b3 = (const float*)d_in[6];
    const float* d3 = (const float*)d_in[7];
    const float* w4 = (const float*)d_in[8];
    const float* b4 = (const float*)d_in[9];
    const float* d4 = (const float*)d_in[10];
    const float* w6 = (const float*)d_in[11];
    const float* b6 = (const float*)d_in[12];
    const float* d6 = (const float*)d_in[13];
    const float* w7 = (const float*)d_in[14];
    const float* b7 = (const float*)d_in[15];
    const float* d7 = (const float*)d_in[16];
    const float* w8 = (const float*)d_in[17];
    const float* b8 = (const float*)d_in[18];
    const float* d8 = (const float*)d_in[19];
    const float* w9 = (const float*)d_in[20];
    const float* b9 = (const float*)d_in[21];
    const float* d9 = (const float*)d_in[22];
    const float* w10 = (const float*)d_in[23];
    const float* b10 = (const float*)d_in[24];
    const float* d10 = (const float*)d_in[25];
    const float* w11 = (const float*)d_in[26];
    const float* b11 = (const float*)d_in[27];
    const float* d11 = (const float*)d_in[28];
    const float* fc1_w = (const float*)d_in[29];
    const float* fc1_b = (const float*)d_in[30];
    const float* bn_g = (const float*)d_in[31];
    const float* bn_b = (const float*)d_in[32];
    const float* bn_m = (const float*)d_in[33];
    const float* bn_v = (const float*)d_in[34];
    const float* fc2_w = (const float*)d_in[35];
    const float* fc2_b = (const float*)d_in[36];
    (void)in_sizes; (void)n_in; (void)out_size; (void)ws_size;

    float* ws = (float*)d_ws;
    size_t off = 0;
    auto alloc = [&](size_t n) { float* p = ws + off; off += n; return p; };
    float* fout = alloc(4 * 256 * 5120);
    int* idx1 = (int*)alloc(4 * 4096 * 32);
    int* idx2 = (int*)alloc(4 * 2048 * 32);
    int* idx3 = (int*)alloc(4 * 1024 * 32);
    int* idx4 = (int*)alloc(4 * 512 * 32);
    int* idx5 = (int*)alloc(4 * 256 * 32);
    float* F1 = alloc(4 * 4096 * 64);
    float* L2 = alloc(4 * 2048 * 128);
    float* L3 = alloc(4 * 1024 * 192);
    float* L4 = alloc(4 * 512 * 256);
    float* L5 = alloc(4 * 256 * 288);
    float* G = alloc(4 * 256 * 1024);
    float4* vp1 = (float4*)alloc((4 * 4096 + 512) * 4);  // padded for prefetch
    float* gm = alloc(4 * 1024);
    float* hh = alloc(4 * 256);

    // bf16 staging for conv11 MFMA aliased into G (G written only at agg_big).
    unsigned short* Abf = (unsigned short*)G;           // 1024*288 bf16
    unsigned short* WTbf = Abf + 1024 * 288;            // 5120*288 bf16

    // ---- Start: pack + (L1 coop qb+surface | qb L2-L5 | castT) ----
    pack4_kernel<<<tblocks(B * 4096), 256, 0, stream>>>(verts1, vp1, B * 4096);
    mega_start_kernel<<<20944, 256, 0, stream>>>(vp1, surf_dirs, F1, 64,
                                                 idx1, idx2, idx3, idx4, idx5,
                                                 w11, WTbf);

    // ---- Level 1 (V=4096) ----
    gemm_tiled_kernel<<<ggrid(B * 4096, 160), 256, 0, stream>>>(F1, 64, 32, w1, b1, 160, fout);
    conv_agg32_kernel<<<B * 4096 / 4, 256, 0, stream>>>(idx1, vp1, fout, d1, F1, 64, 32, 4096, 1, nullptr);
    pool_fused_kernel<<<wblocks(B * 2048), 256, 0, stream>>>(idx1, 4096, 2048, B, F1, 64, L2, 128, 64, nullptr);

    // ---- Level 2 (V=2048) ----
    gemm_tiled_kernel<<<ggrid(B * 2048, 160), 256, 0, stream>>>(L2, 128, 64, w3, b3, 160, fout);
    conv_agg32_kernel<<<B * 2048 / 4, 256, 0, stream>>>(idx2, vp1, fout, d3, L2, 128, 64, 2048, 1, nullptr);
    gemm_tiled_kernel<<<ggrid(B * 2048, 160), 256, 0, stream>>>(L2, 128, 96, w4, b4, 160, fout);
    conv_agg32_kernel<<<B * 2048 / 4, 256, 0, stream>>>(idx2, vp1, fout, d4, L2, 128, 96, 2048, 1, nullptr);
    pool_fused_kernel<<<wblocks(B * 1024), 256, 0, stream>>>(idx2, 2048, 1024, B, L2, 128, L3, 192, 128, nullptr);

    // ---- Level 3 (V=1024) ----
    gemm_tiled_kernel<<<ggrid(B * 1024, 160), 256, 0, stream>>>(L3, 192, 128, w6, b6, 160, fout);
    conv_agg32_kernel<<<B * 1024 / 4, 256, 0, stream>>>(idx3, vp1, fout, d6, L3, 192, 128, 1024, 1, nullptr);
    gemm_tiled_kernel<<<ggrid(B * 1024, 160), 256, 0, stream>>>(L3, 192, 160, w7, b7, 160, fout);
    conv_agg32_kernel<<<B * 1024 / 4, 256, 0, stream>>>(idx3, vp1, fout, d7, L3, 192, 160, 1024, 1, nullptr);
    pool_fused_kernel<<<wblocks(B * 512), 256, 0, stream>>>(idx3, 1024, 512, B, L3, 192, L4, 256, 192, nullptr);

    // ---- Level 4 (V=512) ----
    gemm_tiled_kernel<<<ggrid(B * 512, 160), 256, 0, stream>>>(L4, 256, 192, w8, b8, 160, fout);
    conv_agg32_kernel<<<B * 512 / 4, 256, 0, stream>>>(idx4, vp1, fout, d8, L4, 256, 192, 512, 1, nullptr);
    gemm_tiled_kernel<<<ggrid(B * 512, 160), 256, 0, stream>>>(L4, 256, 224, w9, b9, 160, fout);
    conv_agg32_kernel<<<B * 512 / 4, 256, 0, stream>>>(idx4, vp1, fout, d9, L4, 256, 224, 512, 1, nullptr);
    pool_fused_kernel<<<wblocks(B * 256), 256, 0, stream>>>(idx4, 512, 256, B, L4, 256, L5, 288, 256, Abf);

    // ---- Level 5 (V=256) ----
    gemm_tiled_kernel<<<ggrid(B * 256, 160), 256, 0, stream>>>(L5, 288, 256, w10, b10, 160, fout);
    conv_agg32_kernel<<<B * 256 / 4, 256, 0, stream>>>(idx5, vp1, fout, d10, L5, 288, 256, 256, 1, Abf);
    __hip_bfloat16* fout_bf = (__hip_bfloat16*)fout;
    gemm_mfma_conv11<<<dim3(8, 40), 256, 0, stream>>>(Abf, WTbf, b11, fout_bf);
    conv_agg_big_kernel<<<B * 256, 512, 0, stream>>>(idx5, vp1, fout_bf, d11, G, 256, B);

    // ---- Head ----
    gmax_kernel<<<64, 256, 0, stream>>>(G, gm, 256);
    fc1_kernel<<<dim3(8, B), 256, 0, stream>>>(gm, fc1_w, fc1_b, bn_g, bn_b, bn_m, bn_v, hh);
    fc2_kernel<<<B, 256, 0, stream>>>(hh, fc2_w, fc2_b, (float*)d_out);
}

// Round 14
// 412.683 us; speedup vs baseline: 1.0716x; 1.0716x over previous
//
#include <hip/hip_runtime.h>
#include <hip/hip_bf16.h>
#include <math.h>

#define DEV __device__ __forceinline__

DEV float frn_mul(float a, float b) { return __fmul_rn(a, b); }
DEV float frn_add(float a, float b) { return __fadd_rn(a, b); }

union BFU { __hip_bfloat16 h; unsigned short u; };

typedef __attribute__((ext_vector_type(8))) short short8v;  // 8 bf16 (4 VGPRs)
typedef __attribute__((ext_vector_type(4))) float f32x4;

// ---------------------------------------------------------------------------
// pack verts [n][3] -> float4 (x,y,z,|p|^2) with pn in exact frn order.
// ---------------------------------------------------------------------------
__global__ void pack4_kernel(const float* __restrict__ v, float4* __restrict__ out,
                             int n)
{
    int t = blockIdx.x * blockDim.x + threadIdx.x;
    if (t >= n) return;
    float x = v[(size_t)t * 3 + 0], y = v[(size_t)t * 3 + 1], z = v[(size_t)t * 3 + 2];
    float pn = frn_add(frn_add(frn_mul(x, x), frn_mul(y, y)), frn_mul(z, z));
    out[t] = make_float4(x, y, z, pn);
}

// ---------------------------------------------------------------------------
// qb scan body, 2-deep pipelined (128-pt granularity). V % 128 == 0.
// pts buffer must allow reads up to V+255 within allocation (padded).
// ---------------------------------------------------------------------------
DEV void qb_scan2(const float4* __restrict__ pts, int V, float4 q4, float r2,
                  int lane, int* __restrict__ row)
{
    float qx = q4.x, qy = q4.y, qz = q4.z, qn = q4.w;
    int count = 0;
    int first = -1;
    float4 pbuf[2];
#pragma unroll
    for (int u = 0; u < 2; ++u) pbuf[u] = pts[u * 64 + lane];
    for (int base = 0; base < V && count < 32; base += 128) {
#pragma unroll
        for (int u = 0; u < 2; ++u) {
            float4 p = pbuf[u];
            pbuf[u] = pts[base + 128 + u * 64 + lane];
            float dt = frn_add(frn_add(frn_mul(qx, p.x), frn_mul(qy, p.y)), frn_mul(qz, p.z));
            float d = __fsub_rn(frn_add(qn, p.w), frn_mul(2.0f, dt));
            bool in = !(d > r2);
            unsigned long long mask = __ballot(in);
            if (first < 0 && mask != 0ull)
                first = base + u * 64 + (int)__ffsll((long long)mask) - 1;
            int pos = count + (int)__popcll(mask & ((1ull << lane) - 1ull));
            if (in && pos < 32) row[pos] = base + u * 64 + lane;
            count += (int)__popcll(mask);
        }
    }
    int cnt = count < 32 ? count : 32;
    for (int t = cnt + lane; t < 32; t += 64) row[t] = first;
}

// ---------------------------------------------------------------------------
// MEGA start kernel: block ranges
//  [0,4096)            : L1 qb(K=32, 4-deep) + conv_surface (one wave/query)
//  [4096,6144)         : qb L2 (V=2048, r2=0.16) -> idx2
//  [6144,7168)         : qb L3 (V=1024, r2=0.36) -> idx3
//  [7168,7680)         : qb L4 (V=512,  r2=0.64) -> idx4
//  [7680,7936)         : qb L5 (V=256,  r2=1.0)  -> idx5
//  [7936,8656)         : castT w11 [288][5120] f32 -> WTbf [5120][288] bf16
// All qb phases read only vp1 (batch stride 4096, padded).
// ---------------------------------------------------------------------------
__global__ __launch_bounds__(256)
void mega_start_kernel(const float4* __restrict__ vp1,
                       const float* __restrict__ dirs, // (3,128) surf
                       float* __restrict__ outF, int Cw,
                       int* __restrict__ idx1, int* __restrict__ idx2,
                       int* __restrict__ idx3, int* __restrict__ idx4,
                       int* __restrict__ idx5,
                       const float* __restrict__ w11, unsigned short* __restrict__ wt)
{
    __shared__ int rowS[4][32];
    int bid = blockIdx.x;
    int tid = threadIdx.x;
    int lane = tid & 63;

    if (bid < 4096) {
        // ---- L1 qb + surface (V=4096, 4-deep pipelined, wave-per-query) ----
        int wid = (bid * 256 + tid) >> 6;
        int wql = tid >> 6;
        int b = wid >> 12;
        float4 q4 = vp1[(size_t)wid];
        float qx = q4.x, qy = q4.y, qz = q4.z, qn = q4.w;
        const float4* pts = vp1 + (size_t)b * 4096;
        int* row = idx1 + (size_t)wid * 32;

        int count = 0;
        int first = -1;
        float4 pbuf[4];
#pragma unroll
        for (int u = 0; u < 4; ++u) pbuf[u] = pts[u * 64 + lane];
        for (int base = 0; base < 4096 && count < 32; base += 256) {
#pragma unroll
            for (int u = 0; u < 4; ++u) {
                float4 p = pbuf[u];
                pbuf[u] = pts[base + 256 + u * 64 + lane];
                float dt = frn_add(frn_add(frn_mul(qx, p.x), frn_mul(qy, p.y)), frn_mul(qz, p.z));
                float d = __fsub_rn(frn_add(qn, p.w), frn_mul(2.0f, dt));
                bool in = !(d > 0.04f);
                unsigned long long mask = __ballot(in);
                if (first < 0 && mask != 0ull)
                    first = base + u * 64 + (int)__ffsll((long long)mask) - 1;
                int pos = count + (int)__popcll(mask & ((1ull << lane) - 1ull));
                if (in && pos < 32) { row[pos] = base + u * 64 + lane; rowS[wql][pos] = base + u * 64 + lane; }
                count += (int)__popcll(mask);
            }
        }
        int cnt = count < 32 ? count : 32;
        for (int t = cnt + lane; t < 32; t += 64) { row[t] = first; rowS[wql][t] = first; }
        __syncthreads();

        float dnx, dny, dnz;
        {
            int k = lane & 31;
            float4 nb4 = pts[rowS[wql][k]];
            float dx = nb4.x - qx;
            float dy = nb4.y - qy;
            float dz = nb4.z - qz;
            float nrm = sqrtf(dx * dx + dy * dy + dz * dz) + 1e-12f;
            float inv = 1.0f / nrm;
            dnx = dx * inv; dny = dy * inv; dnz = dz * inv;
        }
        int m1 = lane, m2 = lane + 64;
        float ax = dirs[m1], ay = dirs[128 + m1], az = dirs[256 + m1];
        float i1 = 1.0f / (sqrtf(ax * ax + ay * ay + az * az) + 1e-12f);
        ax *= i1; ay *= i1; az *= i1;
        float bx = dirs[m2], by = dirs[128 + m2], bz = dirs[256 + m2];
        float i2 = 1.0f / (sqrtf(bx * bx + by * by + bz * bz) + 1e-12f);
        bx *= i2; by *= i2; bz *= i2;

        float mx1 = -INFINITY, mx2 = -INFINITY;
        for (int k = 0; k < 32; ++k) {
            float ex = __shfl(dnx, k, 64);
            float ey = __shfl(dny, k, 64);
            float ez = __shfl(dnz, k, 64);
            float t1 = fmaxf(ex * ax + ey * ay + ez * az, 0.0f);
            float t2 = fmaxf(ex * bx + ey * by + ez * bz, 0.0f);
            mx1 = fmaxf(mx1, t1);
            mx2 = fmaxf(mx2, t2);
        }
        float part = mx1 + mx2;
        float tot = part + __shfl_xor(part, 32, 64);
        if (lane < 32) {
            outF[(size_t)wid * Cw + lane] = fmaxf(tot, 0.0f);
        }
    } else if (bid < 7936) {
        int V, r_bid; float r2; int* idxp;
        if (bid < 6144)      { V = 2048; r2 = 0.16f; idxp = idx2; r_bid = bid - 4096; }
        else if (bid < 7168) { V = 1024; r2 = 0.36f; idxp = idx3; r_bid = bid - 6144; }
        else if (bid < 7680) { V = 512;  r2 = 0.64f; idxp = idx4; r_bid = bid - 7168; }
        else                 { V = 256;  r2 = 1.0f;  idxp = idx5; r_bid = bid - 7680; }
        int widl = (r_bid * 256 + tid) >> 6;      // 0 .. 4*V-1
        int b = widl / V;
        int v = widl - b * V;
        float4 q4 = vp1[(size_t)b * 4096 + v];
        const float4* pts = vp1 + (size_t)b * 4096;
        qb_scan2(pts, V, q4, r2, lane, idxp + (size_t)widl * 32);
    } else {
        // ---- castT: w11 -> WTbf ----
        int t = (bid - 7936) * 256 + tid;
        if (t < 5120 * 36) {
            int kc = t / 5120;
            int n = t - kc * 5120;
            BFU a;
            ushort4 o0, o1;
            a.h = __float2bfloat16(w11[(size_t)(kc * 8 + 0) * 5120 + n]); o0.x = a.u;
            a.h = __float2bfloat16(w11[(size_t)(kc * 8 + 1) * 5120 + n]); o0.y = a.u;
            a.h = __float2bfloat16(w11[(size_t)(kc * 8 + 2) * 5120 + n]); o0.z = a.u;
            a.h = __float2bfloat16(w11[(size_t)(kc * 8 + 3) * 5120 + n]); o0.w = a.u;
            a.h = __float2bfloat16(w11[(size_t)(kc * 8 + 4) * 5120 + n]); o1.x = a.u;
            a.h = __float2bfloat16(w11[(size_t)(kc * 8 + 5) * 5120 + n]); o1.y = a.u;
            a.h = __float2bfloat16(w11[(size_t)(kc * 8 + 6) * 5120 + n]); o1.z = a.u;
            a.h = __float2bfloat16(w11[(size_t)(kc * 8 + 7) * 5120 + n]); o1.w = a.u;
            *(ushort4*)&wt[(size_t)n * 288 + kc * 8] = o0;
            *(ushort4*)&wt[(size_t)n * 288 + kc * 8 + 4] = o1;
        }
    }
}

// ---------------------------------------------------------------------------
// Tiled GEMM (64x64, 4x4 micro): small-N layer GEMMs (fp32, proven).
// ---------------------------------------------------------------------------
__global__ __launch_bounds__(256)
void gemm_tiled_kernel(const float* __restrict__ feat, int Cw, int cin,
                       const float* __restrict__ w, const float* __restrict__ bias,
                       int N, float* __restrict__ fout)
{
    __shared__ float As[64][36];
    __shared__ float Bs[32][68];

    int m0 = blockIdx.x * 64;
    int n0 = blockIdx.y * 64;
    int tid = threadIdx.x;
    int tx = tid & 15, ty = tid >> 4;

    float acc[4][4];
#pragma unroll
    for (int i = 0; i < 4; ++i)
#pragma unroll
        for (int j = 0; j < 4; ++j) acc[i][j] = 0.0f;

    for (int k0 = 0; k0 < cin; k0 += 32) {
#pragma unroll
        for (int i = 0; i < 2; ++i) {
            int qq = tid + i * 256;
            int row = qq >> 3, c = qq & 7;
            float4 v = *(const float4*)&feat[(size_t)(m0 + row) * Cw + k0 + 4 * c];
            *(float4*)&As[row][4 * c] = v;
        }
#pragma unroll
        for (int i = 0; i < 2; ++i) {
            int qq = tid + i * 256;
            int kr = qq >> 4, c = qq & 15;
            int n = n0 + 4 * c;
            float4 v = make_float4(0.0f, 0.0f, 0.0f, 0.0f);
            if (n < N) v = *(const float4*)&w[(size_t)(k0 + kr) * N + n];
            *(float4*)&Bs[kr][4 * c] = v;
        }
        __syncthreads();

#pragma unroll
        for (int kt = 0; kt < 32; kt += 4) {
            float4 av4[4], bv4[4];
#pragma unroll
            for (int i = 0; i < 4; ++i) av4[i] = *(const float4*)&As[ty * 4 + i][kt];
#pragma unroll
            for (int r = 0; r < 4; ++r) bv4[r] = *(const float4*)&Bs[kt + r][tx * 4];
            const float* a = (const float*)av4;
            const float* bb = (const float*)bv4;
#pragma unroll
            for (int i = 0; i < 4; ++i)
#pragma unroll
                for (int r = 0; r < 4; ++r)
#pragma unroll
                    for (int j = 0; j < 4; ++j)
                        acc[i][j] = fmaf(a[i * 4 + r], bb[r * 4 + j], acc[i][j]);
        }
        __syncthreads();
    }

    int n = n0 + tx * 4;
    if (n < N) {
        float b0 = bias[n + 0], b1 = bias[n + 1], b2 = bias[n + 2], b3 = bias[n + 3];
#pragma unroll
        for (int i = 0; i < 4; ++i) {
            int m = m0 + ty * 4 + i;
            float4 o;
            o.x = acc[i][0] + b0;
            o.y = acc[i][1] + b1;
            o.z = acc[i][2] + b2;
            o.w = acc[i][3] + b3;
            *(float4*)&fout[(size_t)m * N + n] = o;
        }
    }
}

// ---------------------------------------------------------------------------
// conv11 GEMM via bf16 MFMA (M=1024, K=288, N=5120). 128x128 tile, 4 waves.
// ---------------------------------------------------------------------------
__global__ __launch_bounds__(256)
void gemm_mfma_conv11(const unsigned short* __restrict__ Abf,
                      const unsigned short* __restrict__ WTbf,
                      const float* __restrict__ bias,
                      __hip_bfloat16* __restrict__ fout)
{
    __shared__ unsigned short As[128][40];
    __shared__ unsigned short Bs[128][40];
    const int K = 288, N = 5120;
    int m0 = blockIdx.x * 128;
    int n0 = blockIdx.y * 128;
    int tid = threadIdx.x;
    int lane = tid & 63;
    int wave = tid >> 6;
    int wm = wave & 1, wn = wave >> 1;
    int l15 = lane & 15, l4 = lane >> 4;

    f32x4 acc[4][4];
#pragma unroll
    for (int mi = 0; mi < 4; ++mi)
#pragma unroll
        for (int ni = 0; ni < 4; ++ni) acc[mi][ni] = (f32x4){0.f, 0.f, 0.f, 0.f};

    for (int k0 = 0; k0 < K; k0 += 32) {
#pragma unroll
        for (int i = 0; i < 2; ++i) {
            int c = tid + i * 256;
            int row = c >> 2, qq = c & 3;
            *(uint4*)&As[row][qq * 8] = *(const uint4*)&Abf[(size_t)(m0 + row) * K + k0 + qq * 8];
            *(uint4*)&Bs[row][qq * 8] = *(const uint4*)&WTbf[(size_t)(n0 + row) * K + k0 + qq * 8];
        }
        __syncthreads();

        short8v af[4], bfv[4];
#pragma unroll
        for (int mi = 0; mi < 4; ++mi)
            af[mi] = *(const short8v*)&As[wm * 64 + mi * 16 + l15][l4 * 8];
#pragma unroll
        for (int ni = 0; ni < 4; ++ni)
            bfv[ni] = *(const short8v*)&Bs[wn * 64 + ni * 16 + l15][l4 * 8];
#pragma unroll
        for (int mi = 0; mi < 4; ++mi)
#pragma unroll
            for (int ni = 0; ni < 4; ++ni)
                acc[mi][ni] = __builtin_amdgcn_mfma_f32_16x16x32_bf16(af[mi], bfv[ni], acc[mi][ni], 0, 0, 0);
        __syncthreads();
    }

#pragma unroll
    for (int ni = 0; ni < 4; ++ni) {
        int col = n0 + wn * 64 + ni * 16 + l15;
        float bv = bias[col];
#pragma unroll
        for (int mi = 0; mi < 4; ++mi) {
            int rbase = m0 + wm * 64 + mi * 16 + l4 * 4;
#pragma unroll
            for (int j = 0; j < 4; ++j) {
                BFU u;
                u.h = __float2bfloat16(acc[mi][ni][j] + bv);
                *(unsigned short*)&fout[(size_t)(rbase + j) * N + col] = u.u;
            }
        }
    }
}

// ---------------------------------------------------------------------------
// conv_layer aggregation, cout=32. One wave per (b,v), XCD-swizzled.
// Verts in vp1 (batch stride 4096). Optional bf16 mirror (L5 -> Abf col 256+).
// ---------------------------------------------------------------------------
__global__ void conv_agg32_kernel(const int* __restrict__ idx,
                                  const float4* __restrict__ vp1,
                                  const float* __restrict__ fout,
                                  const float* __restrict__ dirs, // (3,128)
                                  float* __restrict__ outF, int Cw, int coff,
                                  int V, int do_relu,
                                  unsigned short* __restrict__ abf)
{
    int blk = blockIdx.x;
    int b = (blk & 7) >> 1;
    int j = ((blk >> 3) << 1) | (blk & 1);
    int vloc = j * 4 + (int)(threadIdx.x >> 6);
    int wid = b * V + vloc;
    int lane = threadIdx.x & 63;

    float dnx, dny, dnz;
    int nbrow;
    {
        int k = lane & 31;
        int nb = idx[(size_t)wid * 32 + k];
        nbrow = b * V + nb;
        float4 c4 = vp1[(size_t)b * 4096 + vloc];
        float4 n4 = vp1[(size_t)b * 4096 + nb];
        float dx = n4.x - c4.x;
        float dy = n4.y - c4.y;
        float dz = n4.z - c4.z;
        float nrm = sqrtf(dx * dx + dy * dy + dz * dz) + 1e-12f;
        float inv = 1.0f / nrm;
        dnx = dx * inv; dny = dy * inv; dnz = dz * inv;
    }
    int m1 = lane, m2 = lane + 64;
    float ax = dirs[m1], ay = dirs[128 + m1], az = dirs[256 + m1];
    float i1 = 1.0f / (sqrtf(ax * ax + ay * ay + az * az) + 1e-12f);
    ax *= i1; ay *= i1; az *= i1;
    float bx = dirs[m2], by = dirs[128 + m2], bz = dirs[256 + m2];
    float i2 = 1.0f / (sqrtf(bx * bx + by * by + bz * bz) + 1e-12f);
    bx *= i2; by *= i2; bz *= i2;

    float a1[4] = {-INFINITY, -INFINITY, -INFINITY, -INFINITY};
    float a2[4] = {-INFINITY, -INFINITY, -INFINITY, -INFINITY};
#pragma unroll
    for (int kk = 0; kk < 32; kk += 4) {
#pragma unroll
        for (int u = 0; u < 4; ++u) {
            int k = kk + u;
            float ex = __shfl(dnx, k, 64);
            float ey = __shfl(dny, k, 64);
            float ez = __shfl(dnz, k, 64);
            int nr = __shfl(nbrow, k, 64);
            const float* fr = fout + (size_t)nr * 160 + 32;
            float t1 = fmaxf(ex * ax + ey * ay + ez * az, 0.0f);
            float t2 = fmaxf(ex * bx + ey * by + ez * bz, 0.0f);
            a1[u] = fmaxf(a1[u], t1 * fr[m1]);
            a2[u] = fmaxf(a2[u], t2 * fr[m2]);
        }
    }
    float mx1 = fmaxf(fmaxf(a1[0], a1[1]), fmaxf(a1[2], a1[3]));
    float mx2 = fmaxf(fmaxf(a2[0], a2[1]), fmaxf(a2[2], a2[3]));
    float part = mx1 + mx2;
    float tot = part + __shfl_xor(part, 32, 64);
    if (lane < 32) {
        float c = fout[(size_t)wid * 160 + lane];
        float val = c + tot;
        if (do_relu) val = fmaxf(val, 0.0f);
        outF[(size_t)wid * Cw + coff + lane] = val;
        if (abf) {
            BFU u; u.h = __float2bfloat16(val);
            abf[(size_t)wid * 288 + coff + lane] = u.u;
        }
    }
}

// ---------------------------------------------------------------------------
// conv11 aggregation: cout=1024. One 512-thread block per (b,v). Thread t
// owns 8 pairs [8t,8t+8). Row offsets hoisted to LDS; k-loop unrolled x2.
// Padded-LDS regroup (pad 9), exact original ((s0+s1)+s2)+s3 order.
// ---------------------------------------------------------------------------
__global__ __launch_bounds__(512)
void conv_agg_big_kernel(const int* __restrict__ idx,
                         const float4* __restrict__ vp1,
                         const __hip_bfloat16* __restrict__ fout,
                         const float* __restrict__ dirs,
                         float* __restrict__ G,
                         int V, int B)
{
    __shared__ float dnS[32][3];
    __shared__ long long offS[32];
    __shared__ float sm[512 * 9];
    int blk = blockIdx.x;
    int b = (blk & 7) >> 1;
    int v = ((blk >> 3) << 1) | (blk & 1);
    int row = b * V + v;
    int tid = threadIdx.x;

    if (tid < 32) {
        int nb = idx[(size_t)row * 32 + tid];
        float4 c4 = vp1[(size_t)b * 4096 + v];
        float4 n4 = vp1[(size_t)b * 4096 + nb];
        float dx = n4.x - c4.x;
        float dy = n4.y - c4.y;
        float dz = n4.z - c4.z;
        float nrm = sqrtf(dx * dx + dy * dy + dz * dz) + 1e-12f;
        float inv = 1.0f / nrm;
        dnS[tid][0] = dx * inv; dnS[tid][1] = dy * inv; dnS[tid][2] = dz * inv;
        offS[tid] = (long long)(b * V + nb) * 5120 + 1024;
    }
    __syncthreads();

    int p0 = tid * 8;
    float4 X[2], Y[2], Z[2];
#pragma unroll
    for (int c = 0; c < 2; ++c) {
        X[c] = *(const float4*)&dirs[p0 + 4 * c];
        Y[c] = *(const float4*)&dirs[4096 + p0 + 4 * c];
        Z[c] = *(const float4*)&dirs[8192 + p0 + 4 * c];
    }
    const float* xf = (const float*)X;
    const float* yf = (const float*)Y;
    const float* zf = (const float*)Z;
    float sdx[8], sdy[8], sdz[8], mx[8];
#pragma unroll
    for (int p = 0; p < 8; ++p) {
        float ax = xf[p], ay = yf[p], az = zf[p];
        float inv = 1.0f / (sqrtf(ax * ax + ay * ay + az * az) + 1e-12f);
        sdx[p] = ax * inv; sdy[p] = ay * inv; sdz[p] = az * inv;
        mx[p] = -INFINITY;
    }

#pragma unroll 2
    for (int k = 0; k < 32; ++k) {
        float ex = dnS[k][0], ey = dnS[k][1], ez = dnS[k][2];
        const __hip_bfloat16* fr = fout + offS[k];
        uint4 u0 = *(const uint4*)&fr[p0];
        unsigned int uu[4] = {u0.x, u0.y, u0.z, u0.w};
#pragma unroll
        for (int h = 0; h < 4; ++h) {
            float slo = __uint_as_float(uu[h] << 16);
            float shi = __uint_as_float(uu[h] & 0xFFFF0000u);
            int p = 2 * h;
            float th0 = fmaxf(ex * sdx[p] + ey * sdy[p] + ez * sdz[p], 0.0f);
            float th1 = fmaxf(ex * sdx[p + 1] + ey * sdy[p + 1] + ez * sdz[p + 1], 0.0f);
            mx[p] = fmaxf(mx[p], th0 * slo);
            mx[p + 1] = fmaxf(mx[p + 1], th1 * shi);
        }
    }

#pragma unroll
    for (int p = 0; p < 8; ++p) sm[tid * 9 + p] = mx[p];
    __syncthreads();

#pragma unroll
    for (int q = 0; q < 2; ++q) {
        int oo = q * 512 + tid;
        int t0 = oo >> 3, pp = oo & 7;
        float s0 = sm[t0 * 9 + pp];
        float s1 = sm[(128 + t0) * 9 + pp];
        float s2 = sm[(256 + t0) * 9 + pp];
        float s3 = sm[(384 + t0) * 9 + pp];
        float val = ((s0 + s1) + s2) + s3;
        float c = __bfloat162float(fout[(size_t)row * 5120 + oo]);
        G[(size_t)row * 1024 + oo] = c + val;
    }
}

// ---------------------------------------------------------------------------
// Pool: reuses conv idx (first 4). Pure feature gather (+ optional bf16
// mirror for the conv11 A-matrix at L4->L5).
// ---------------------------------------------------------------------------
__global__ void pool_fused_kernel(const int* __restrict__ idx_conv,
                                  int Vp, int Vh, int B,
                                  const float* __restrict__ Fin, int CwIn,
                                  float* __restrict__ Fout, int CwOut, int C,
                                  unsigned short* __restrict__ abf)
{
    int wid = (blockIdx.x * blockDim.x + threadIdx.x) >> 6;
    int lane = threadIdx.x & 63;
    int nq = B * Vh;
    if (wid >= nq) return;
    int b = wid / Vh;
    int v = wid - b * Vh;
    int rowc = b * Vp + v;

    int idv = 0;
    if (lane < 4) idv = idx_conv[(size_t)rowc * 32 + lane];
    int i0 = __shfl(idv, 0, 64);
    int i1 = __shfl(idv, 1, 64);
    int i2 = __shfl(idv, 2, 64);
    int i3 = __shfl(idv, 3, 64);

    const float* r0 = Fin + (size_t)(b * Vp + i0) * CwIn;
    const float* r1 = Fin + (size_t)(b * Vp + i1) * CwIn;
    const float* r2p = Fin + (size_t)(b * Vp + i2) * CwIn;
    const float* r3 = Fin + (size_t)(b * Vp + i3) * CwIn;
    for (int c = lane; c < C; c += 64) {
        float m = fmaxf(fmaxf(r0[c], r1[c]), fmaxf(r2p[c], r3[c]));
        Fout[(size_t)wid * CwOut + c] = m;
        if (abf) {
            BFU u; u.h = __float2bfloat16(m);
            abf[(size_t)wid * 288 + c] = u.u;
        }
    }
}

// ---------------------------------------------------------------------------
// Head
// ---------------------------------------------------------------------------
__global__ void gmax_kernel(const float* __restrict__ G, float* __restrict__ gm,
                            int V)
{
    __shared__ float red[4][64];
    int b = blockIdx.x >> 4;
    int c0 = (blockIdx.x & 15) * 64;
    int t = threadIdx.x;
    int c = c0 + (t & 63);
    int vg = t >> 6;
    float m = -INFINITY;
    for (int v = vg * 64; v < (vg + 1) * 64; ++v)
        m = fmaxf(m, G[((size_t)b * V + v) * 1024 + c]);
    red[vg][t & 63] = m;
    __syncthreads();
    if (t < 64) {
        float r = fmaxf(fmaxf(red[0][t], red[1][t]), fmaxf(red[2][t], red[3][t]));
        gm[b * 1024 + c0 + t] = r;
    }
}

__global__ __launch_bounds__(256)
void fc1_kernel(const float* __restrict__ gm, const float* __restrict__ w1,
                const float* __restrict__ b1_,
                const float* __restrict__ bn_g, const float* __restrict__ bn_b,
                const float* __restrict__ bn_m, const float* __restrict__ bn_v,
                float* __restrict__ h)
{
    __shared__ float gs[1024];
    __shared__ float red[8][32];
    int b = blockIdx.y;
    int j0 = blockIdx.x * 32;
    int t = threadIdx.x;
    for (int i = t; i < 1024; i += 256) gs[i] = gm[b * 1024 + i];
    __syncthreads();
    int jj = t & 31, kk = t >> 5;
    int j = j0 + jj;
    const float* wp = w1 + (size_t)(kk * 128) * 256 + j;
    float acc = 0.0f;
#pragma unroll 8
    for (int k = 0; k < 128; ++k)
        acc = fmaf(gs[kk * 128 + k], wp[(size_t)k * 256], acc);
    red[kk][jj] = acc;
    __syncthreads();
    if (t < 32) {
        float s = 0.0f;
#pragma unroll
        for (int q = 0; q < 8; ++q) s += red[q][t];
        int jw = j0 + t;
        s += b1_[jw];
        s = (s - bn_m[jw]) / sqrtf(bn_v[jw] + 1e-5f) * bn_g[jw] + bn_b[jw];
        h[b * 256 + jw] = fmaxf(s, 0.0f);
    }
}

__global__ void fc2_kernel(const float* __restrict__ h, const float* __restrict__ w2,
                           const float* __restrict__ b2_, float* __restrict__ out)
{
    __shared__ float hs[256];
    int b = blockIdx.x;
    int t = threadIdx.x;
    hs[t] = h[b * 256 + t];
    __syncthreads();
    if (t < 40) {
        float acc = 0.0f;
#pragma unroll 8
        for (int k = 0; k < 256; ++k) acc = fmaf(hs[k], w2[(size_t)k * 40 + t], acc);
        out[b * 40 + t] = acc + b2_[t];
    }
}

// ---------------------------------------------------------------------------
static inline int wblocks(int waves) { return (waves + 3) / 4; }
static inline int tblocks(int threads) { return (threads + 255) / 256; }
static inline dim3 ggrid(int M, int N) { return dim3(M / 64, (N + 63) / 64); }

extern "C" void kernel_launch(void* const* d_in, const int* in_sizes, int n_in,
                              void* d_out, int out_size, void* d_ws, size_t ws_size,
                              hipStream_t stream)
{
    const int B = 4;
    const float* verts1 = (const float*)d_in[0];
    const float* surf_dirs = (const float*)d_in[1];
    const float* w1 = (const float*)d_in[2];
    const float* b1 = (const float*)d_in[3];
    const float* d1 = (const float*)d_in[4];
    const float* w3 = (const float*)d_in[5];
    const float* b3 = (const float*)d_in[6];
    const float* d3 = (const float*)d_in[7];
    const float* w4 = (const float*)d_in[8];
    const float* b4 = (const float*)d_in[9];
    const float* d4 = (const float*)d_in[10];
    const float* w6 = (const float*)d_in[11];
    const float* b6 = (const float*)d_in[12];
    const float* d6 = (const float*)d_in[13];
    const float* w7 = (const float*)d_in[14];
    const float* b7 = (const float*)d_in[15];
    const float* d7 = (const float*)d_in[16];
    const float* w8 = (const float*)d_in[17];
    const float* b8 = (const float*)d_in[18];
    const float* d8 = (const float*)d_in[19];
    const float* w9 = (const float*)d_in[20];
    const float* b9 = (const float*)d_in[21];
    const float* d9 = (const float*)d_in[22];
    const float* w10 = (const float*)d_in[23];
    const float* b10 = (const float*)d_in[24];
    const float* d10 = (const float*)d_in[25];
    const float* w11 = (const float*)d_in[26];
    const float* b11 = (const float*)d_in[27];
    const float* d11 = (const float*)d_in[28];
    const float* fc1_w = (const float*)d_in[29];
    const float* fc1_b = (const float*)d_in[30];
    const float* bn_g = (const float*)d_in[31];
    const float* bn_b = (const float*)d_in[32];
    const float* bn_m = (const float*)d_in[33];
    const float* bn_v = (const float*)d_in[34];
    const float* fc2_w = (const float*)d_in[35];
    const float* fc2_b = (const float*)d_in[36];
    (void)in_sizes; (void)n_in; (void)out_size; (void)ws_size;

    float* ws = (float*)d_ws;
    size_t off = 0;
    auto alloc = [&](size_t n) { float* p = ws + off; off += n; return p; };
    float* fout = alloc(4 * 256 * 5120);
    int* idx1 = (int*)alloc(4 * 4096 * 32);
    int* idx2 = (int*)alloc(4 * 2048 * 32);
    int* idx3 = (int*)alloc(4 * 1024 * 32);
    int* idx4 = (int*)alloc(4 * 512 * 32);
    int* idx5 = (int*)alloc(4 * 256 * 32);
    float* F1 = alloc(4 * 4096 * 64);
    float* L2 = alloc(4 * 2048 * 128);
    float* L3 = alloc(4 * 1024 * 192);
    float* L4 = alloc(4 * 512 * 256);
    float* L5 = alloc(4 * 256 * 288);
    float* G = alloc(4 * 256 * 1024);
    float4* vp1 = (float4*)alloc((4 * 4096 + 512) * 4);  // padded for prefetch
    float* gm = alloc(4 * 1024);
    float* hh = alloc(4 * 256);

    // bf16 staging for conv11 MFMA aliased into G (G written only at agg_big).
    unsigned short* Abf = (unsigned short*)G;           // 1024*288 bf16
    unsigned short* WTbf = Abf + 1024 * 288;            // 5120*288 bf16

    // ---- Start: pack + (L1 qb+surface | qb L2-L5 | castT) ----
    pack4_kernel<<<tblocks(B * 4096), 256, 0, stream>>>(verts1, vp1, B * 4096);
    mega_start_kernel<<<8656, 256, 0, stream>>>(vp1, surf_dirs, F1, 64,
                                                idx1, idx2, idx3, idx4, idx5,
                                                w11, WTbf);

    // ---- Level 1 (V=4096) ----
    gemm_tiled_kernel<<<ggrid(B * 4096, 160), 256, 0, stream>>>(F1, 64, 32, w1, b1, 160, fout);
    conv_agg32_kernel<<<B * 4096 / 4, 256, 0, stream>>>(idx1, vp1, fout, d1, F1, 64, 32, 4096, 1, nullptr);
    pool_fused_kernel<<<wblocks(B * 2048), 256, 0, stream>>>(idx1, 4096, 2048, B, F1, 64, L2, 128, 64, nullptr);

    // ---- Level 2 (V=2048) ----
    gemm_tiled_kernel<<<ggrid(B * 2048, 160), 256, 0, stream>>>(L2, 128, 64, w3, b3, 160, fout);
    conv_agg32_kernel<<<B * 2048 / 4, 256, 0, stream>>>(idx2, vp1, fout, d3, L2, 128, 64, 2048, 1, nullptr);
    gemm_tiled_kernel<<<ggrid(B * 2048, 160), 256, 0, stream>>>(L2, 128, 96, w4, b4, 160, fout);
    conv_agg32_kernel<<<B * 2048 / 4, 256, 0, stream>>>(idx2, vp1, fout, d4, L2, 128, 96, 2048, 1, nullptr);
    pool_fused_kernel<<<wblocks(B * 1024), 256, 0, stream>>>(idx2, 2048, 1024, B, L2, 128, L3, 192, 128, nullptr);

    // ---- Level 3 (V=1024) ----
    gemm_tiled_kernel<<<ggrid(B * 1024, 160), 256, 0, stream>>>(L3, 192, 128, w6, b6, 160, fout);
    conv_agg32_kernel<<<B * 1024 / 4, 256, 0, stream>>>(idx3, vp1, fout, d6, L3, 192, 128, 1024, 1, nullptr);
    gemm_tiled_kernel<<<ggrid(B * 1024, 160), 256, 0, stream>>>(L3, 192, 160, w7, b7, 160, fout);
    conv_agg32_kernel<<<B * 1024 / 4, 256, 0, stream>>>(idx3, vp1, fout, d7, L3, 192, 160, 1024, 1, nullptr);
    pool_fused_kernel<<<wblocks(B * 512), 256, 0, stream>>>(idx3, 1024, 512, B, L3, 192, L4, 256, 192, nullptr);

    // ---- Level 4 (V=512) ----
    gemm_tiled_kernel<<<ggrid(B * 512, 160), 256, 0, stream>>>(L4, 256, 192, w8, b8, 160, fout);
    conv_agg32_kernel<<<B * 512 / 4, 256, 0, stream>>>(idx4, vp1, fout, d8, L4, 256, 192, 512, 1, nullptr);
    gemm_tiled_kernel<<<ggrid(B * 512, 160), 256, 0, stream>>>(L4, 256, 224, w9, b9, 160, fout);
    conv_agg32_kernel<<<B * 512 / 4, 256, 0, stream>>>(idx4, vp1, fout, d9, L4, 256, 224, 512, 1, nullptr);
    pool_fused_kernel<<<wblocks(B * 256), 256, 0, stream>>>(idx4, 512, 256, B, L4, 256, L5, 288, 256, Abf);

    // ---- Level 5 (V=256) ----
    gemm_tiled_kernel<<<ggrid(B * 256, 160), 256, 0, stream>>>(L5, 288, 256, w10, b10, 160, fout);
    conv_agg32_kernel<<<B * 256 / 4, 256, 0, stream>>>(idx5, vp1, fout, d10, L5, 288, 256, 256, 1, Abf);
    __hip_bfloat16* fout_bf = (__hip_bfloat16*)fout;
    gemm_mfma_conv11<<<dim3(8, 40), 256, 0, stream>>>(Abf, WTbf, b11, fout_bf);
    conv_agg_big_kernel<<<B * 256, 512, 0, stream>>>(idx5, vp1, fout_bf, d11, G, 256, B);

    // ---- Head ----
    gmax_kernel<<<64, 256, 0, stream>>>(G, gm, 256);
    fc1_kernel<<<dim3(8, B), 256, 0, stream>>>(gm, fc1_w, fc1_b, bn_g, bn_b, bn_m, bn_v, hh);
    fc2_kernel<<<B, 256, 0, stream>>>(hh, fc2_w, fc2_b, (float*)d_out);
}